// Round 1
// baseline (1269.610 us; speedup 1.0000x reference)
//
#include <hip/hip_runtime.h>
#include <cstdint>

#define DEV __device__ __forceinline__

typedef __attribute__((ext_vector_type(8))) __bf16 bf16x8;
typedef __attribute__((ext_vector_type(4))) float f32x4;

DEV unsigned short f2bf(float f) {
  unsigned int u = __float_as_uint(f);
  u += 0x7FFFu + ((u >> 16) & 1u);
  return (unsigned short)(u >> 16);
}
DEV float bf2f(unsigned short h) { return __uint_as_float(((unsigned int)h) << 16); }

// async global->LDS, 16B per lane. LDS dest is wave-uniform base + lane*16.
DEV void async_ld16(const void* g, void* l) {
  __builtin_amdgcn_global_load_lds(
      (__attribute__((address_space(1))) unsigned int*)(uintptr_t)g,
      (__attribute__((address_space(3))) unsigned int*)(uint32_t)(uintptr_t)l,
      16, 0, 0);
}

// ---------------------------------------------------------------------------
// NT-GEMM: C[M x N] = A[M x K] * B[N x K]^T   (both K-contiguous, bf16-as-ushort)
// BM x BN tile, BK=32, 4 waves in 2x2 grid, 16x16x32 bf16 MFMA.
// M % BM == 0, N % BN == 0, K % 32 == 0 assumed (true for all our shapes).
// ---------------------------------------------------------------------------
template <int BM, int BN, bool OUTF32, bool RELU, bool HASBIAS>
__global__ __launch_bounds__(256) void gemm_nt(
    const unsigned short* __restrict__ A, const unsigned short* __restrict__ B,
    void* __restrict__ Cp, const float* __restrict__ bias,
    int K, int lda, int ldb, int ldc) {
  constexpr int BK = 32;
  constexpr int WM = BM / 2, WN = BN / 2;
  constexpr int FM = WM / 16, FN = WN / 16;

  __shared__ unsigned short As[BM * BK];
  __shared__ unsigned short Bs[BN * BK];

  const int tid = threadIdx.x;
  const int wave = tid >> 6, lane = tid & 63;
  const int wm = (wave >> 1) * WM, wn = (wave & 1) * WN;
  const int bm = blockIdx.y * BM, bn = blockIdx.x * BN;

  const int r4 = tid >> 2;          // row covered by this thread in a 64-row part
  const int c4 = (tid & 3) * 8;     // k-offset (8 bf16 = 16B)

  f32x4 acc[FM][FN] = {};

  const int kq = (lane >> 4) * 8;   // fragment k base: quad*8
  const int mr = lane & 15;         // fragment row/col within 16

  for (int k0 = 0; k0 < K; k0 += BK) {
    // stage A tile: BM rows x 32 bf16; each 64-thread wave stages 16 rows/issue
#pragma unroll
    for (int p = 0; p < BM / 64; ++p) {
      const unsigned short* g = A + (size_t)(bm + p * 64 + r4) * lda + k0 + c4;
      async_ld16(g, &As[p * 2048 + wave * 512]);
    }
#pragma unroll
    for (int p = 0; p < BN / 64; ++p) {
      const unsigned short* g = B + (size_t)(bn + p * 64 + r4) * ldb + k0 + c4;
      async_ld16(g, &Bs[p * 2048 + wave * 512]);
    }
    __syncthreads();

    bf16x8 av[FM], bv[FN];
#pragma unroll
    for (int i = 0; i < FM; ++i)
      av[i] = *(const bf16x8*)(const void*)&As[(wm + i * 16 + mr) * BK + kq];
#pragma unroll
    for (int j = 0; j < FN; ++j)
      bv[j] = *(const bf16x8*)(const void*)&Bs[(wn + j * 16 + mr) * BK + kq];

#pragma unroll
    for (int i = 0; i < FM; ++i)
#pragma unroll
      for (int j = 0; j < FN; ++j)
        acc[i][j] = __builtin_amdgcn_mfma_f32_16x16x32_bf16(av[i], bv[j], acc[i][j], 0, 0, 0);

    __syncthreads();
  }

  // epilogue: C/D layout col=lane&15, row=(lane>>4)*4+reg
  const int quad = lane >> 4;
#pragma unroll
  for (int i = 0; i < FM; ++i) {
#pragma unroll
    for (int j = 0; j < FN; ++j) {
      const int col = bn + wn + j * 16 + mr;
      float bv_ = 0.f;
      if (HASBIAS) bv_ = bias[col];
#pragma unroll
      for (int r = 0; r < 4; ++r) {
        const int row = bm + wm + i * 16 + quad * 4 + r;
        float v = acc[i][j][r];
        if (HASBIAS) v += bv_;
        if (RELU) v = fmaxf(v, 0.f);
        if (OUTF32)
          ((float*)Cp)[(size_t)row * ldc + col] = v;
        else
          ((unsigned short*)Cp)[(size_t)row * ldc + col] = f2bf(v);
      }
    }
  }
}

// ---------------------------------------------------------------------------
// Build split-bf16 Q/K matrices: QQ = [qh | qh | ql], KK = [kh | kl | kh]
// so that QQ . KK^T = qh.kh + qh.kl + ql.kh  (fp32-grade logits from bf16 MFMA)
// ---------------------------------------------------------------------------
__global__ __launch_bounds__(256) void build_qqkk(
    const float* __restrict__ Q, const float* __restrict__ Km,
    unsigned short* __restrict__ QQ, unsigned short* __restrict__ KK) {
  const size_t idx = (size_t)blockIdx.x * 256 + threadIdx.x;  // over 8192*768
  const int i = (int)(idx / 768), j = (int)(idx % 768);
  const size_t base = (size_t)i * 2304 + j;
  float q = Q[idx];
  unsigned short qh = f2bf(q);
  unsigned short ql = f2bf(q - bf2f(qh));
  QQ[base] = qh; QQ[base + 768] = qh; QQ[base + 1536] = ql;
  float k = Km[idx];
  unsigned short kh = f2bf(k);
  unsigned short kl = f2bf(k - bf2f(kh));
  KK[base] = kh; KK[base + 768] = kl; KK[base + 1536] = kh;
}

// V [8192 x 768] fp32 -> vT [768 x 8192] bf16 (K-contiguous for the P*V GEMM)
__global__ __launch_bounds__(256) void vt_kernel(const float* __restrict__ V,
                                                 unsigned short* __restrict__ vT) {
  __shared__ float t[32][33];
  const int bx = blockIdx.x, by = blockIdx.y;
  const int x = threadIdx.x, y = threadIdx.y;  // (32, 8)
#pragma unroll
  for (int r = 0; r < 4; ++r)
    t[y + r * 8][x] = V[(size_t)(by * 32 + y + r * 8) * 768 + bx * 32 + x];
  __syncthreads();
#pragma unroll
  for (int r = 0; r < 4; ++r)
    vT[(size_t)(bx * 32 + y + r * 8) * 8192 + by * 32 + x] = f2bf(t[x][y + r * 8]);
}

__global__ __launch_bounds__(256) void cvt_bf16(const float* __restrict__ in,
                                                unsigned short* __restrict__ out, int n) {
  int i = blockIdx.x * 256 + threadIdx.x;
  if (i < n) out[i] = f2bf(in[i]);
}

// Row softmax over 8192 fp32 logits, writes normalized bf16 P in-place into the
// first half of the same row (row stride stays 8192 floats = 16384 bf16).
__global__ __launch_bounds__(256) void softmax_rows(float* __restrict__ S) {
  const int row = blockIdx.x;
  const int tid = threadIdx.x;
  const int wave = tid >> 6, lane = tid & 63;
  float* Sr = S + (size_t)row * 8192;

  f32x4 v[8];
  const f32x4* src = (const f32x4*)Sr;
#pragma unroll
  for (int c = 0; c < 8; ++c) v[c] = src[c * 256 + tid];

  float m = -1e30f;
#pragma unroll
  for (int c = 0; c < 8; ++c)
#pragma unroll
    for (int e = 0; e < 4; ++e) m = fmaxf(m, v[c][e]);
#pragma unroll
  for (int o = 32; o > 0; o >>= 1) m = fmaxf(m, __shfl_xor(m, o));
  __shared__ float redm[4];
  if (lane == 0) redm[wave] = m;
  __syncthreads();
  m = fmaxf(fmaxf(redm[0], redm[1]), fmaxf(redm[2], redm[3]));

  float sum = 0.f;
#pragma unroll
  for (int c = 0; c < 8; ++c)
#pragma unroll
    for (int e = 0; e < 4; ++e) {
      float ev = __expf(v[c][e] - m);
      v[c][e] = ev;
      sum += ev;
    }
#pragma unroll
  for (int o = 32; o > 0; o >>= 1) sum += __shfl_xor(sum, o);
  __shared__ float reds[4];
  if (lane == 0) reds[wave] = sum;
  __syncthreads();
  sum = reds[0] + reds[1] + reds[2] + reds[3];
  const float inv = 1.f / sum;

  unsigned short* P = (unsigned short*)Sr;
#pragma unroll
  for (int c = 0; c < 8; ++c) {
    unsigned int u0 = (unsigned int)f2bf(v[c][0] * inv) | ((unsigned int)f2bf(v[c][1] * inv) << 16);
    unsigned int u1 = (unsigned int)f2bf(v[c][2] * inv) | ((unsigned int)f2bf(v[c][3] * inv) << 16);
    uint2 o2; o2.x = u0; o2.y = u1;
    *(uint2*)(P + c * 1024 + tid * 4) = o2;
  }
}

// ---------------------------------------------------------------------------
extern "C" void kernel_launch(void* const* d_in, const int* in_sizes, int n_in,
                              void* d_out, int out_size, void* d_ws, size_t ws_size,
                              hipStream_t stream) {
  const int N = 8192, D = 768, DFF = 2048, KS = 2304;
  const float* Q  = (const float*)d_in[0];
  const float* Km = (const float*)d_in[1];
  const float* V  = (const float*)d_in[2];
  const float* W1 = (const float*)d_in[3];
  const float* b1 = (const float*)d_in[4];
  const float* W2 = (const float*)d_in[5];
  const float* b2 = (const float*)d_in[6];

  char* w = (char*)d_ws;
  size_t off = 0;
  auto take = [&](size_t bytes) { void* p = w + off; off += bytes; return p; };
  unsigned short* QQ  = (unsigned short*)take((size_t)N * KS * 2);
  unsigned short* KK  = (unsigned short*)take((size_t)N * KS * 2);
  unsigned short* vT  = (unsigned short*)take((size_t)N * D * 2);
  unsigned short* ctx = (unsigned short*)take((size_t)N * D * 2);
  unsigned short* hb  = (unsigned short*)take((size_t)N * DFF * 2);
  unsigned short* w1b = (unsigned short*)take((size_t)DFF * D * 2);
  unsigned short* w2b = (unsigned short*)take((size_t)D * DFF * 2);
  float* S = (float*)(w + off);
  const size_t avail = ws_size > off ? ws_size - off : 0;
  int chunk = 256;  // floor fallback
  const int cands[5] = {8192, 4096, 2048, 1024, 512};
  for (int i = 0; i < 5; ++i)
    if ((size_t)cands[i] * N * 4 <= avail) { chunk = cands[i]; break; }

  build_qqkk<<<(N * D) / 256, 256, 0, stream>>>(Q, Km, QQ, KK);
  vt_kernel<<<dim3(D / 32, N / 32), dim3(32, 8), 0, stream>>>(V, vT);
  cvt_bf16<<<(DFF * D) / 256, 256, 0, stream>>>(W1, w1b, DFF * D);
  cvt_bf16<<<(D * DFF) / 256, 256, 0, stream>>>(W2, w2b, D * DFF);

  for (int r0 = 0; r0 < N; r0 += chunk) {
    const int Mc = chunk;
    // S[Mc x 8192] = QQ_chunk . KK^T  (split-bf16, fp32 logits)
    gemm_nt<128, 128, true, false, false>
        <<<dim3(N / 128, Mc / 128), 256, 0, stream>>>(
            QQ + (size_t)r0 * KS, KK, S, nullptr, KS, KS, KS, N);
    // row softmax, bf16 P in-place (row stride 16384 bf16)
    softmax_rows<<<Mc, 256, 0, stream>>>(S);
    // ctx_chunk[Mc x 768] = P . V  (bf16 out)
    gemm_nt<128, 64, false, false, false>
        <<<dim3(D / 64, Mc / 128), 256, 0, stream>>>(
            (const unsigned short*)S, vT, ctx + (size_t)r0 * D, nullptr,
            N, 2 * N, N, D);
  }

  // h = relu(ctx . W1^T + b1)  [8192 x 2048] bf16
  gemm_nt<128, 128, false, true, true>
      <<<dim3(DFF / 128, N / 128), 256, 0, stream>>>(
          ctx, w1b, hb, b1, D, D, D, DFF);
  // out = h . W2^T + b2  [8192 x 768] fp32
  gemm_nt<128, 64, true, false, true>
      <<<dim3(D / 64, N / 128), 256, 0, stream>>>(
          hb, w2b, (float*)d_out, b2, DFF, DFF, DFF, D);
}

// Round 2
// 817.029 us; speedup vs baseline: 1.5539x; 1.5539x over previous
//
#include <hip/hip_runtime.h>
#include <cstdint>

#define DEV __device__ __forceinline__

typedef _Float16 f16;
typedef __attribute__((ext_vector_type(8))) _Float16 f16x8;
typedef __attribute__((ext_vector_type(4))) float f32x4;

DEV unsigned short f2h(float f) {
  f16 h = (f16)f;
  return __builtin_bit_cast(unsigned short, h);
}

// async global->LDS, 16B per lane. LDS dest is wave-uniform base + lane*16.
DEV void async_ld16(const void* g, void* l) {
  __builtin_amdgcn_global_load_lds(
      (__attribute__((address_space(1))) unsigned int*)(uintptr_t)g,
      (__attribute__((address_space(3))) unsigned int*)(uint32_t)(uintptr_t)l,
      16, 0, 0);
}

// ---------------------------------------------------------------------------
// NT-GEMM: C[M x N] = A[M x K] * B[N x K]^T   (both K-contiguous, f16-as-ushort)
// BM x BN tile, BK=32, 4 waves in 2x2 grid, 16x16x32 f16 MFMA.
// blockIdx.z = K-slice (A/B advance by z*K elements); ATOMIC accumulates fp32.
// ---------------------------------------------------------------------------
template <int BM, int BN, bool OUTF32, bool RELU, bool HASBIAS, bool ATOMIC>
__global__ __launch_bounds__(256) void gemm_nt(
    const unsigned short* __restrict__ A, const unsigned short* __restrict__ B,
    void* __restrict__ Cp, const float* __restrict__ bias,
    int K, int lda, int ldb, int ldc) {
  constexpr int BK = 32;
  constexpr int WM = BM / 2, WN = BN / 2;
  constexpr int FM = WM / 16, FN = WN / 16;

  __shared__ __align__(16) unsigned short As[BM * BK];
  __shared__ __align__(16) unsigned short Bs[BN * BK];

  const int tid = threadIdx.x;
  const int wave = tid >> 6, lane = tid & 63;
  const int wm = (wave >> 1) * WM, wn = (wave & 1) * WN;
  const int bm = blockIdx.y * BM, bn = blockIdx.x * BN;
  const size_t koff = (size_t)blockIdx.z * K;

  const int r4 = tid >> 2;          // row covered by this thread in a 64-row part
  const int c4 = (tid & 3) * 8;     // k-offset (8 f16 = 16B)

  f32x4 acc[FM][FN] = {};

  const int kq = (lane >> 4) * 8;   // fragment k base: quad*8
  const int mr = lane & 15;         // fragment row/col within 16

  for (int k0 = 0; k0 < K; k0 += BK) {
#pragma unroll
    for (int p = 0; p < BM / 64; ++p) {
      const unsigned short* g = A + (size_t)(bm + p * 64 + r4) * lda + koff + k0 + c4;
      async_ld16(g, &As[p * 2048 + wave * 512]);
    }
#pragma unroll
    for (int p = 0; p < BN / 64; ++p) {
      const unsigned short* g = B + (size_t)(bn + p * 64 + r4) * ldb + koff + k0 + c4;
      async_ld16(g, &Bs[p * 2048 + wave * 512]);
    }
    __syncthreads();

    f16x8 av[FM], bv[FN];
#pragma unroll
    for (int i = 0; i < FM; ++i)
      av[i] = *(const f16x8*)(const void*)&As[(wm + i * 16 + mr) * BK + kq];
#pragma unroll
    for (int j = 0; j < FN; ++j)
      bv[j] = *(const f16x8*)(const void*)&Bs[(wn + j * 16 + mr) * BK + kq];

#pragma unroll
    for (int i = 0; i < FM; ++i)
#pragma unroll
      for (int j = 0; j < FN; ++j)
        acc[i][j] = __builtin_amdgcn_mfma_f32_16x16x32_f16(av[i], bv[j], acc[i][j], 0, 0, 0);

    __syncthreads();
  }

  // epilogue: C/D layout col=lane&15, row=(lane>>4)*4+reg
  const int quad = lane >> 4;
#pragma unroll
  for (int i = 0; i < FM; ++i) {
#pragma unroll
    for (int j = 0; j < FN; ++j) {
      const int col = bn + wn + j * 16 + mr;
      float bv_ = 0.f;
      if (HASBIAS) bv_ = bias[col];
#pragma unroll
      for (int r = 0; r < 4; ++r) {
        const int row = bm + wm + i * 16 + quad * 4 + r;
        float v = acc[i][j][r];
        if (HASBIAS) v += bv_;
        if (RELU) v = fmaxf(v, 0.f);
        if (ATOMIC)
          atomicAdd(&((float*)Cp)[(size_t)row * ldc + col], v);
        else if (OUTF32)
          ((float*)Cp)[(size_t)row * ldc + col] = v;
        else
          ((unsigned short*)Cp)[(size_t)row * ldc + col] = f2h(v);
      }
    }
  }
}

// fp32 -> fp16 bulk convert
__global__ __launch_bounds__(256) void cvt_f16(const float* __restrict__ in,
                                               unsigned short* __restrict__ out, int n) {
  int i = blockIdx.x * 256 + threadIdx.x;
  if (i < n) out[i] = f2h(in[i]);
}

// V [8192 x 768] fp32 -> vT [768 x 8192] fp16 (K-contiguous for the P*V GEMM)
__global__ __launch_bounds__(256) void vt_kernel(const float* __restrict__ V,
                                                 unsigned short* __restrict__ vT) {
  __shared__ float t[32][33];
  const int bx = blockIdx.x, by = blockIdx.y;
  const int x = threadIdx.x, y = threadIdx.y;  // (32, 8)
#pragma unroll
  for (int r = 0; r < 4; ++r)
    t[y + r * 8][x] = V[(size_t)(by * 32 + y + r * 8) * 768 + bx * 32 + x];
  __syncthreads();
#pragma unroll
  for (int r = 0; r < 4; ++r)
    vT[(size_t)(bx * 32 + y + r * 8) * 8192 + by * 32 + x] = f2h(t[x][y + r * 8]);
}

// Row softmax over 8192 fp32 logits, writes normalized fp16 P in-place into the
// first half of the same row (row stride stays 8192 floats = 16384 halves).
__global__ __launch_bounds__(256) void softmax_rows(float* __restrict__ S) {
  const int row = blockIdx.x;
  const int tid = threadIdx.x;
  const int wave = tid >> 6, lane = tid & 63;
  float* Sr = S + (size_t)row * 8192;

  f32x4 v[8];
  const f32x4* src = (const f32x4*)Sr;
#pragma unroll
  for (int c = 0; c < 8; ++c) v[c] = src[c * 256 + tid];

  float m = -1e30f;
#pragma unroll
  for (int c = 0; c < 8; ++c)
#pragma unroll
    for (int e = 0; e < 4; ++e) m = fmaxf(m, v[c][e]);
#pragma unroll
  for (int o = 32; o > 0; o >>= 1) m = fmaxf(m, __shfl_xor(m, o));
  __shared__ float redm[4];
  if (lane == 0) redm[wave] = m;
  __syncthreads();
  m = fmaxf(fmaxf(redm[0], redm[1]), fmaxf(redm[2], redm[3]));

  float sum = 0.f;
#pragma unroll
  for (int c = 0; c < 8; ++c)
#pragma unroll
    for (int e = 0; e < 4; ++e) {
      float ev = __expf(v[c][e] - m);
      v[c][e] = ev;
      sum += ev;
    }
#pragma unroll
  for (int o = 32; o > 0; o >>= 1) sum += __shfl_xor(sum, o);
  __shared__ float reds[4];
  if (lane == 0) reds[wave] = sum;
  __syncthreads();
  sum = reds[0] + reds[1] + reds[2] + reds[3];
  const float inv = 1.f / sum;

  unsigned short* P = (unsigned short*)Sr;
#pragma unroll
  for (int c = 0; c < 8; ++c) {
    unsigned int u0 = (unsigned int)f2h(v[c][0] * inv) | ((unsigned int)f2h(v[c][1] * inv) << 16);
    unsigned int u1 = (unsigned int)f2h(v[c][2] * inv) | ((unsigned int)f2h(v[c][3] * inv) << 16);
    uint2 o2; o2.x = u0; o2.y = u1;
    *(uint2*)(P + c * 1024 + tid * 4) = o2;
  }
}

// ---------------------------------------------------------------------------
extern "C" void kernel_launch(void* const* d_in, const int* in_sizes, int n_in,
                              void* d_out, int out_size, void* d_ws, size_t ws_size,
                              hipStream_t stream) {
  const int N = 8192, D = 768, DFF = 2048;
  const float* Q  = (const float*)d_in[0];
  const float* Km = (const float*)d_in[1];
  const float* V  = (const float*)d_in[2];
  const float* W1 = (const float*)d_in[3];
  const float* b1 = (const float*)d_in[4];
  const float* W2 = (const float*)d_in[5];
  const float* b2 = (const float*)d_in[6];

  char* w = (char*)d_ws;
  size_t off = 0;
  auto take = [&](size_t bytes) { void* p = w + off; off += bytes; return p; };
  unsigned short* qh   = (unsigned short*)take((size_t)N * D * 2);
  unsigned short* kh   = (unsigned short*)take((size_t)N * D * 2);
  unsigned short* vT   = (unsigned short*)take((size_t)N * D * 2);
  unsigned short* ctx16= (unsigned short*)take((size_t)N * D * 2);
  float*          ctx32= (float*)take((size_t)N * D * 4);
  unsigned short* hb   = (unsigned short*)take((size_t)N * DFF * 2);
  unsigned short* w1h  = (unsigned short*)take((size_t)DFF * D * 2);
  unsigned short* w2h  = (unsigned short*)take((size_t)D * DFF * 2);
  float* S = (float*)(w + off);
  const size_t avail = ws_size > off ? ws_size - off : 0;
  int chunk = 512;  // floor fallback
  const int cands[5] = {8192, 4096, 2048, 1024, 512};
  for (int i = 0; i < 5; ++i)
    if ((size_t)cands[i] * N * 4 <= avail) { chunk = cands[i]; break; }
  const int slices = N / chunk;  // PV split-K factor -> grid >= ~768 blocks

  cvt_f16<<<(N * D) / 256, 256, 0, stream>>>(Q, qh, N * D);
  cvt_f16<<<(N * D) / 256, 256, 0, stream>>>(Km, kh, N * D);
  vt_kernel<<<dim3(D / 32, N / 32), dim3(32, 8), 0, stream>>>(V, vT);
  cvt_f16<<<(DFF * D) / 256, 256, 0, stream>>>(W1, w1h, DFF * D);
  cvt_f16<<<(D * DFF) / 256, 256, 0, stream>>>(W2, w2h, D * DFF);
  hipMemsetAsync(ctx32, 0, (size_t)N * D * 4, stream);

  for (int r0 = 0; r0 < N; r0 += chunk) {
    const int Mc = chunk;
    // S[Mc x 8192] = Q_chunk . K^T  (fp16 inputs, fp32 logits)
    gemm_nt<128, 128, true, false, false, false>
        <<<dim3(N / 128, Mc / 128), 256, 0, stream>>>(
            qh + (size_t)r0 * D, kh, S, nullptr, D, D, D, N);
    // row softmax, fp16 P in-place (row stride 16384 halves)
    softmax_rows<<<Mc, 256, 0, stream>>>(S);
    // ctx32_chunk[Mc x 768] += P . V  (split-K over slices, fp32 atomic)
    gemm_nt<128, 64, true, false, false, true>
        <<<dim3(D / 64, Mc / 128, slices), 256, 0, stream>>>(
            (const unsigned short*)S, vT, ctx32 + (size_t)r0 * D, nullptr,
            N / slices, 2 * N, N, D);
  }

  cvt_f16<<<(N * D) / 256, 256, 0, stream>>>(ctx32, ctx16, N * D);

  // h = relu(ctx . W1^T + b1)  [8192 x 2048] fp16
  gemm_nt<128, 128, false, true, true, false>
      <<<dim3(DFF / 128, N / 128), 256, 0, stream>>>(
          ctx16, w1h, hb, b1, D, D, D, DFF);
  // out = h . W2^T + b2  [8192 x 768] fp32
  gemm_nt<128, 64, true, false, true, false>
      <<<dim3(D / 64, N / 128), 256, 0, stream>>>(
          hb, w2h, (float*)d_out, b2, DFF, DFF, DFF, D);
}

// Round 3
// 742.551 us; speedup vs baseline: 1.7098x; 1.1003x over previous
//
#include <hip/hip_runtime.h>
#include <cstdint>

#define DEV __device__ __forceinline__

typedef _Float16 f16;
typedef __attribute__((ext_vector_type(8))) _Float16 f16x8;
typedef __attribute__((ext_vector_type(4))) float f32x4;

DEV unsigned short f2h(float f) {
  f16 h = (f16)f;
  return __builtin_bit_cast(unsigned short, h);
}

// async global->LDS, 16B per lane. LDS dest is wave-uniform base + lane*16.
DEV void async_ld16(const void* g, void* l) {
  __builtin_amdgcn_global_load_lds(
      (__attribute__((address_space(1))) unsigned int*)(uintptr_t)g,
      (__attribute__((address_space(3))) unsigned int*)(uint32_t)(uintptr_t)l,
      16, 0, 0);
}

// ---------------------------------------------------------------------------
// NT-GEMM: C[M x N] = A[M x K] * B[N x K]^T   (both K-contiguous, f16-as-ushort)
// BM x BN tile, BK=32, 4 waves in 2x2 grid, 16x16x32 f16 MFMA.
// 1D grid of nt*mt*sl blocks, decomposed with an XCD-aware swizzle: all blocks
// sharing an M-slab (same A rows) land on the same XCD so the A re-reads hit
// that XCD's private 4MB L2 instead of HBM. sl = split-K slices (ATOMIC fp32).
// ---------------------------------------------------------------------------
template <int BM, int BN, bool OUTF32, bool RELU, bool HASBIAS, bool ATOMIC>
__global__ __launch_bounds__(256) void gemm_nt(
    const unsigned short* __restrict__ A, const unsigned short* __restrict__ B,
    void* __restrict__ Cp, const float* __restrict__ bias,
    int K, int lda, int ldb, int ldc, int nt, int mt, int sl) {
  constexpr int BK = 32;
  constexpr int WM = BM / 2, WN = BN / 2;
  constexpr int FM = WM / 16, FN = WN / 16;

  __shared__ __align__(16) unsigned short As[BM * BK];
  __shared__ __align__(16) unsigned short Bs[BN * BK];

  // ---- XCD-aware block swizzle (assumes HW maps linear id round-robin %8) --
  int mb, nb, zb;
  {
    const int b = blockIdx.x;
    if ((mt & 7) == 0) {
      const int xcd = b & 7;
      const int i = b >> 3;
      const int per = nt * sl;          // blocks per M-slab
      mb = xcd + 8 * (i / per);
      const int j = i % per;
      zb = j / nt;
      nb = j % nt;
    } else {
      nb = b % nt;
      const int t = b / nt;
      mb = t % mt;
      zb = t / mt;
    }
  }

  const int tid = threadIdx.x;
  const int wave = tid >> 6, lane = tid & 63;
  const int wm = (wave >> 1) * WM, wn = (wave & 1) * WN;
  const int bm = mb * BM, bn = nb * BN;
  const size_t koff = (size_t)zb * K;

  const int r4 = tid >> 2;          // row covered by this thread in a 64-row part
  const int c4 = (tid & 3) * 8;     // k-offset (8 f16 = 16B)

  f32x4 acc[FM][FN] = {};

  const int kq = (lane >> 4) * 8;   // fragment k base: quad*8
  const int mr = lane & 15;         // fragment row/col within 16

  for (int k0 = 0; k0 < K; k0 += BK) {
#pragma unroll
    for (int p = 0; p < BM / 64; ++p) {
      const unsigned short* g = A + (size_t)(bm + p * 64 + r4) * lda + koff + k0 + c4;
      async_ld16(g, &As[p * 2048 + wave * 512]);
    }
#pragma unroll
    for (int p = 0; p < BN / 64; ++p) {
      const unsigned short* g = B + (size_t)(bn + p * 64 + r4) * ldb + koff + k0 + c4;
      async_ld16(g, &Bs[p * 2048 + wave * 512]);
    }
    __syncthreads();

    f16x8 av[FM], bv[FN];
#pragma unroll
    for (int i = 0; i < FM; ++i)
      av[i] = *(const f16x8*)(const void*)&As[(wm + i * 16 + mr) * BK + kq];
#pragma unroll
    for (int j = 0; j < FN; ++j)
      bv[j] = *(const f16x8*)(const void*)&Bs[(wn + j * 16 + mr) * BK + kq];

#pragma unroll
    for (int i = 0; i < FM; ++i)
#pragma unroll
      for (int j = 0; j < FN; ++j)
        acc[i][j] = __builtin_amdgcn_mfma_f32_16x16x32_f16(av[i], bv[j], acc[i][j], 0, 0, 0);

    __syncthreads();
  }

  // epilogue: C/D layout col=lane&15, row=(lane>>4)*4+reg
  const int quad = lane >> 4;
#pragma unroll
  for (int i = 0; i < FM; ++i) {
#pragma unroll
    for (int j = 0; j < FN; ++j) {
      const int col = bn + wn + j * 16 + mr;
      float bv_ = 0.f;
      if (HASBIAS) bv_ = bias[col];
#pragma unroll
      for (int r = 0; r < 4; ++r) {
        const int row = bm + wm + i * 16 + quad * 4 + r;
        float v = acc[i][j][r];
        if (HASBIAS) v += bv_;
        if (RELU) v = fmaxf(v, 0.f);
        if (ATOMIC)
          atomicAdd(&((float*)Cp)[(size_t)row * ldc + col], v);
        else if (OUTF32)
          ((float*)Cp)[(size_t)row * ldc + col] = v;
        else
          ((unsigned short*)Cp)[(size_t)row * ldc + col] = f2h(v);
      }
    }
  }
}

// fp32 -> fp16 bulk convert
__global__ __launch_bounds__(256) void cvt_f16(const float* __restrict__ in,
                                               unsigned short* __restrict__ out, int n) {
  int i = blockIdx.x * 256 + threadIdx.x;
  if (i < n) out[i] = f2h(in[i]);
}

// V [8192 x 768] fp32 -> vT [768 x 8192] fp16 (K-contiguous for the P*V GEMM)
__global__ __launch_bounds__(256) void vt_kernel(const float* __restrict__ V,
                                                 unsigned short* __restrict__ vT) {
  __shared__ float t[32][33];
  const int bx = blockIdx.x, by = blockIdx.y;
  const int x = threadIdx.x, y = threadIdx.y;  // (32, 8)
#pragma unroll
  for (int r = 0; r < 4; ++r)
    t[y + r * 8][x] = V[(size_t)(by * 32 + y + r * 8) * 768 + bx * 32 + x];
  __syncthreads();
#pragma unroll
  for (int r = 0; r < 4; ++r)
    vT[(size_t)(bx * 32 + y + r * 8) * 8192 + by * 32 + x] = f2h(t[x][y + r * 8]);
}

// Row softmax over 8192 fp32 logits, writes normalized fp16 P in-place into the
// first half of the same row (row stride stays 8192 floats = 16384 halves).
__global__ __launch_bounds__(256) void softmax_rows(float* __restrict__ S) {
  const int row = blockIdx.x;
  const int tid = threadIdx.x;
  const int wave = tid >> 6, lane = tid & 63;
  float* Sr = S + (size_t)row * 8192;

  f32x4 v[8];
  const f32x4* src = (const f32x4*)Sr;
#pragma unroll
  for (int c = 0; c < 8; ++c) v[c] = src[c * 256 + tid];

  float m = -1e30f;
#pragma unroll
  for (int c = 0; c < 8; ++c)
#pragma unroll
    for (int e = 0; e < 4; ++e) m = fmaxf(m, v[c][e]);
#pragma unroll
  for (int o = 32; o > 0; o >>= 1) m = fmaxf(m, __shfl_xor(m, o));
  __shared__ float redm[4];
  if (lane == 0) redm[wave] = m;
  __syncthreads();
  m = fmaxf(fmaxf(redm[0], redm[1]), fmaxf(redm[2], redm[3]));

  float sum = 0.f;
#pragma unroll
  for (int c = 0; c < 8; ++c)
#pragma unroll
    for (int e = 0; e < 4; ++e) {
      float ev = __expf(v[c][e] - m);
      v[c][e] = ev;
      sum += ev;
    }
#pragma unroll
  for (int o = 32; o > 0; o >>= 1) sum += __shfl_xor(sum, o);
  __shared__ float reds[4];
  if (lane == 0) reds[wave] = sum;
  __syncthreads();
  sum = reds[0] + reds[1] + reds[2] + reds[3];
  const float inv = 1.f / sum;

  unsigned short* P = (unsigned short*)Sr;
#pragma unroll
  for (int c = 0; c < 8; ++c) {
    unsigned int u0 = (unsigned int)f2h(v[c][0] * inv) | ((unsigned int)f2h(v[c][1] * inv) << 16);
    unsigned int u1 = (unsigned int)f2h(v[c][2] * inv) | ((unsigned int)f2h(v[c][3] * inv) << 16);
    uint2 o2; o2.x = u0; o2.y = u1;
    *(uint2*)(P + c * 1024 + tid * 4) = o2;
  }
}

// ---------------------------------------------------------------------------
extern "C" void kernel_launch(void* const* d_in, const int* in_sizes, int n_in,
                              void* d_out, int out_size, void* d_ws, size_t ws_size,
                              hipStream_t stream) {
  const int N = 8192, D = 768, DFF = 2048;
  const float* Q  = (const float*)d_in[0];
  const float* Km = (const float*)d_in[1];
  const float* V  = (const float*)d_in[2];
  const float* W1 = (const float*)d_in[3];
  const float* b1 = (const float*)d_in[4];
  const float* W2 = (const float*)d_in[5];
  const float* b2 = (const float*)d_in[6];

  char* w = (char*)d_ws;
  size_t off = 0;
  auto take = [&](size_t bytes) { void* p = w + off; off += bytes; return p; };
  unsigned short* qh   = (unsigned short*)take((size_t)N * D * 2);
  unsigned short* kh   = (unsigned short*)take((size_t)N * D * 2);
  unsigned short* vT   = (unsigned short*)take((size_t)N * D * 2);
  unsigned short* ctx16= (unsigned short*)take((size_t)N * D * 2);
  float*          ctx32= (float*)take((size_t)N * D * 4);
  unsigned short* hb   = (unsigned short*)take((size_t)N * DFF * 2);
  unsigned short* w1h  = (unsigned short*)take((size_t)DFF * D * 2);
  unsigned short* w2h  = (unsigned short*)take((size_t)D * DFF * 2);
  float* S = (float*)(w + off);
  const size_t avail = ws_size > off ? ws_size - off : 0;
  int chunk = 512;  // floor fallback
  const int cands[4] = {4096, 2048, 1024, 512};
  for (int i = 0; i < 4; ++i)
    if ((size_t)cands[i] * N * 4 <= avail) { chunk = cands[i]; break; }

  cvt_f16<<<(N * D) / 256, 256, 0, stream>>>(Q, qh, N * D);
  cvt_f16<<<(N * D) / 256, 256, 0, stream>>>(Km, kh, N * D);
  vt_kernel<<<dim3(D / 32, N / 32), dim3(32, 8), 0, stream>>>(V, vT);
  cvt_f16<<<(DFF * D) / 256, 256, 0, stream>>>(W1, w1h, DFF * D);
  cvt_f16<<<(D * DFF) / 256, 256, 0, stream>>>(W2, w2h, D * DFF);
  hipMemsetAsync(ctx32, 0, (size_t)N * D * 4, stream);

  // PV split-K: 8 slices -> (D/128)*(chunk/128)*8 blocks (768 at chunk=2048)
  const int sl_pv = 8;

  for (int r0 = 0; r0 < N; r0 += chunk) {
    const int Mc = chunk;
    {  // S[Mc x 8192] = Q_chunk . K^T  (fp16 inputs, fp32 logits)
      const int nt = N / 128, mt = Mc / 128;
      gemm_nt<128, 128, true, false, false, false>
          <<<nt * mt, 256, 0, stream>>>(
              qh + (size_t)r0 * D, kh, S, nullptr, D, D, D, N, nt, mt, 1);
    }
    softmax_rows<<<Mc, 256, 0, stream>>>(S);
    {  // ctx32_chunk[Mc x 768] += P . V  (split-K, fp32 atomic)
      const int nt = D / 128, mt = Mc / 128;
      gemm_nt<128, 128, true, false, false, true>
          <<<nt * mt * sl_pv, 256, 0, stream>>>(
              (const unsigned short*)S, vT, ctx32 + (size_t)r0 * D, nullptr,
              N / sl_pv, 2 * N, N, D, nt, mt, sl_pv);
    }
  }

  cvt_f16<<<(N * D) / 256, 256, 0, stream>>>(ctx32, ctx16, N * D);

  {  // h = relu(ctx . W1^T + b1)  [8192 x 2048] fp16
    const int nt = DFF / 128, mt = N / 128;
    gemm_nt<128, 128, false, true, true, false>
        <<<nt * mt, 256, 0, stream>>>(
            ctx16, w1h, hb, b1, D, D, D, DFF, nt, mt, 1);
  }
  {  // out = h . W2^T + b2  [8192 x 768] fp32
    const int nt = D / 128, mt = N / 128;
    gemm_nt<128, 128, true, false, true, false>
        <<<nt * mt, 256, 0, stream>>>(
            hb, w2h, (float*)d_out, b2, DFF, DFF, DFF, D, nt, mt, 1);
  }
}

// Round 4
// 679.770 us; speedup vs baseline: 1.8677x; 1.0924x over previous
//
#include <hip/hip_runtime.h>
#include <cstdint>

#define DEV __device__ __forceinline__

typedef _Float16 f16;
typedef __attribute__((ext_vector_type(8))) _Float16 f16x8;
typedef __attribute__((ext_vector_type(4))) float f32x4;

DEV unsigned short f2h(float f) {
  f16 h = (f16)f;
  return __builtin_bit_cast(unsigned short, h);
}

DEV void async_ld16(const void* g, void* l) {
  __builtin_amdgcn_global_load_lds(
      (__attribute__((address_space(1))) unsigned int*)(uintptr_t)g,
      (__attribute__((address_space(3))) unsigned int*)(uint32_t)(uintptr_t)l,
      16, 0, 0);
}

// ---------------------------------------------------------------------------
// NT-GEMM: C[M x N] = A[M x K] * B[N x K]^T   (K-contiguous, f16-as-ushort)
// 128x128 tile, BK=32, 4 waves (2x2), 16x16x32 f16 MFMA, global_load_lds x16.
// EPI: 0 = fp16 store, 1 = fp32 store, 2 = fp32 atomicAdd, 3 = exp+stats
//      (writes P' = exp(S - m_tile) fp16 + per-(row,tile) m/l stats).
// ALPHA: scale A-fragments in-loop by alpha[row][k0/128] (fp16, staged in LDS).
// ORDER: within-XCD block order: 0 = mloc-inner (B-slab reuse, short-K),
//        1 = rest-inner (A-slab stays L2-resident, deep-K).
// Grid is 1D = nt*mt*sl; sl = split-K slices (K param = per-slice depth).
// ---------------------------------------------------------------------------
template <int BM, int BN, int EPI, bool RELU, bool HASBIAS, bool ALPHA, int ORDER>
__global__ __launch_bounds__(256) void gemm_nt(
    const unsigned short* __restrict__ A, const unsigned short* __restrict__ B,
    void* __restrict__ Cp, const float* __restrict__ bias,
    const unsigned short* __restrict__ alp, float* __restrict__ stm,
    float* __restrict__ stl, int Mtot,
    int K, int lda, int ldb, int ldc, int nt, int mt, int sl) {
  constexpr int BK = 32;
  constexpr int WM = BM / 2, WN = BN / 2;
  constexpr int FM = WM / 16, FN = WN / 16;

  __shared__ __align__(16) unsigned short As[BM * BK];
  __shared__ __align__(16) unsigned short Bs[BN * BK];
  __shared__ __align__(16) unsigned short Alds[ALPHA ? BM * 64 : 8];

  // ---- XCD-aware swizzle (HW maps linear block id round-robin over 8 XCDs) -
  int mb, nb, zb;
  {
    const int b = blockIdx.x;
    if ((mt & 7) == 0) {
      const int xcd = b & 7;
      const int i = b >> 3;
      const int band_sz = 8 * nt * sl;
      const int band = i / band_sz;
      const int wq = i % band_sz;
      int mloc, rest;
      if (ORDER == 0) { mloc = wq & 7; rest = wq >> 3; }
      else           { rest = wq % (nt * sl); mloc = wq / (nt * sl); }
      mb = xcd + 8 * (band * 8 + mloc);
      nb = rest % nt;
      zb = rest / nt;
    } else {
      nb = b % nt;
      const int t = b / nt;
      mb = t % mt;
      zb = t / mt;
    }
  }

  const int tid = threadIdx.x;
  const int wave = tid >> 6, lane = tid & 63;
  const int wm = (wave >> 1) * WM, wn = (wave & 1) * WN;
  const int bm = mb * BM, bn = nb * BN;
  const size_t koff = (size_t)zb * K;

  const int r4 = tid >> 2;
  const int c4 = (tid & 3) * 8;

  if (ALPHA) {  // stage alpha[bm..bm+127][0..63] fp16 -> 16 KB LDS
    const uint4* g = (const uint4*)(alp + (size_t)bm * 64);
    uint4* s = (uint4*)Alds;
#pragma unroll
    for (int p = 0; p < 4; ++p) s[tid + p * 256] = g[tid + p * 256];
  }

  f32x4 acc[FM][FN] = {};

  const int kq = (lane >> 4) * 8;
  const int mr = lane & 15;
  const int quad = lane >> 4;

  for (int k0 = 0; k0 < K; k0 += BK) {
#pragma unroll
    for (int p = 0; p < BM / 64; ++p) {
      const unsigned short* g = A + (size_t)(bm + p * 64 + r4) * lda + koff + k0 + c4;
      async_ld16(g, &As[p * 2048 + wave * 512]);
    }
#pragma unroll
    for (int p = 0; p < BN / 64; ++p) {
      const unsigned short* g = B + (size_t)(bn + p * 64 + r4) * ldb + koff + k0 + c4;
      async_ld16(g, &Bs[p * 2048 + wave * 512]);
    }
    __syncthreads();

    f16x8 av[FM], bv[FN];
#pragma unroll
    for (int i = 0; i < FM; ++i)
      av[i] = *(const f16x8*)(const void*)&As[(wm + i * 16 + mr) * BK + kq];
#pragma unroll
    for (int j = 0; j < FN; ++j)
      bv[j] = *(const f16x8*)(const void*)&Bs[(wn + j * 16 + mr) * BK + kq];

    if (ALPHA) {
      const int tile = (int)((koff + k0) >> 7);
#pragma unroll
      for (int i = 0; i < FM; ++i) {
        const f16 sc = ((const f16*)Alds)[(wm + i * 16 + mr) * 64 + tile];
        av[i] = av[i] * sc;
      }
    }

#pragma unroll
    for (int i = 0; i < FM; ++i)
#pragma unroll
      for (int j = 0; j < FN; ++j)
        acc[i][j] = __builtin_amdgcn_mfma_f32_16x16x32_f16(av[i], bv[j], acc[i][j], 0, 0, 0);

    __syncthreads();
  }

  if (EPI == 3) {
    // --- fused exp + per-(row, 128-tile) stats ---------------------------
    // C/D layout: col = wn + j*16 + mr, row = wm + i*16 + quad*4 + r
    float* sred = (float*)As;   // [128][2] per-wave-column row max
    float* ssum = (float*)Bs;   // [128][2] per-wave-column row expsum
    const int wc = wave & 1;
    float mt_[FM][4];
#pragma unroll
    for (int i = 0; i < FM; ++i)
#pragma unroll
      for (int r = 0; r < 4; ++r) {
        float m = acc[i][0][r];
#pragma unroll
        for (int j = 1; j < FN; ++j) m = fmaxf(m, acc[i][j][r]);
        m = fmaxf(m, __shfl_xor(m, 1));
        m = fmaxf(m, __shfl_xor(m, 2));
        m = fmaxf(m, __shfl_xor(m, 4));
        m = fmaxf(m, __shfl_xor(m, 8));
        if (mr == 0) sred[(wm + i * 16 + quad * 4 + r) * 2 + wc] = m;
      }
    __syncthreads();
#pragma unroll
    for (int i = 0; i < FM; ++i)
#pragma unroll
      for (int r = 0; r < 4; ++r) {
        const int row_l = wm + i * 16 + quad * 4 + r;
        mt_[i][r] = fmaxf(sred[row_l * 2], sred[row_l * 2 + 1]);
        float l = 0.f;
#pragma unroll
        for (int j = 0; j < FN; ++j) {
          float e = __expf(acc[i][j][r] - mt_[i][r]);
          ((unsigned short*)Cp)[(size_t)(bm + row_l) * ldc + (bn + wn + j * 16 + mr)] = f2h(e);
          l += e;
        }
        l += __shfl_xor(l, 1);
        l += __shfl_xor(l, 2);
        l += __shfl_xor(l, 4);
        l += __shfl_xor(l, 8);
        if (mr == 0) ssum[row_l * 2 + wc] = l;
      }
    __syncthreads();
    if (wc == 0 && mr == 0) {
#pragma unroll
      for (int i = 0; i < FM; ++i)
#pragma unroll
        for (int r = 0; r < 4; ++r) {
          const int row_l = wm + i * 16 + quad * 4 + r;
          stm[(size_t)nb * Mtot + bm + row_l] = mt_[i][r];
          stl[(size_t)nb * Mtot + bm + row_l] = ssum[row_l * 2] + ssum[row_l * 2 + 1];
        }
    }
    return;
  }

  // --- standard epilogue ---------------------------------------------------
#pragma unroll
  for (int i = 0; i < FM; ++i) {
#pragma unroll
    for (int j = 0; j < FN; ++j) {
      const int col = bn + wn + j * 16 + mr;
      float bv_ = 0.f;
      if (HASBIAS) bv_ = bias[col];
#pragma unroll
      for (int r = 0; r < 4; ++r) {
        const int row = bm + wm + i * 16 + quad * 4 + r;
        float v = acc[i][j][r];
        if (HASBIAS) v += bv_;
        if (RELU) v = fmaxf(v, 0.f);
        if (EPI == 2)
          atomicAdd(&((float*)Cp)[(size_t)row * ldc + col], v);
        else if (EPI == 1)
          ((float*)Cp)[(size_t)row * ldc + col] = v;
        else
          ((unsigned short*)Cp)[(size_t)row * ldc + col] = f2h(v);
      }
    }
  }
}

// per-row combine: M = max_t m_t, L = sum_t l_t*exp(m_t-M), alpha = exp(m_t-M)/L
__global__ __launch_bounds__(256) void combine_alpha(
    const float* __restrict__ stm, const float* __restrict__ stl,
    unsigned short* __restrict__ alp, int ntile, int Mtot) {
  const int row = blockIdx.x * 4 + (threadIdx.x >> 6);
  const int t = threadIdx.x & 63;
  float m = (t < ntile) ? stm[(size_t)t * Mtot + row] : -1e30f;
  float M = m;
#pragma unroll
  for (int o = 1; o < 64; o <<= 1) M = fmaxf(M, __shfl_xor(M, o));
  float l = (t < ntile) ? stl[(size_t)t * Mtot + row] : 0.f;
  float c = l * __expf(m - M);
#pragma unroll
  for (int o = 1; o < 64; o <<= 1) c += __shfl_xor(c, o);
  if (t < ntile) alp[(size_t)row * ntile + t] = f2h(__expf(m - M) / c);
}

__global__ __launch_bounds__(256) void cvt_f16(const float* __restrict__ in,
                                               unsigned short* __restrict__ out, int n) {
  int i = blockIdx.x * 256 + threadIdx.x;
  if (i < n) out[i] = f2h(in[i]);
}

__global__ __launch_bounds__(256) void bias_fill(float* __restrict__ out,
                                                 const float* __restrict__ b, int d) {
  int i = blockIdx.x * 256 + threadIdx.x;
  out[i] = b[i % d];
}

// V [8192 x 768] fp32 -> vT [768 x 8192] fp16
__global__ __launch_bounds__(256) void vt_kernel(const float* __restrict__ V,
                                                 unsigned short* __restrict__ vT) {
  __shared__ float t[32][33];
  const int bx = blockIdx.x, by = blockIdx.y;
  const int x = threadIdx.x, y = threadIdx.y;  // (32, 8)
#pragma unroll
  for (int r = 0; r < 4; ++r)
    t[y + r * 8][x] = V[(size_t)(by * 32 + y + r * 8) * 768 + bx * 32 + x];
  __syncthreads();
#pragma unroll
  for (int r = 0; r < 4; ++r)
    vT[(size_t)(bx * 32 + y + r * 8) * 8192 + by * 32 + x] = f2h(t[x][y + r * 8]);
}

// ---------------------------------------------------------------------------
extern "C" void kernel_launch(void* const* d_in, const int* in_sizes, int n_in,
                              void* d_out, int out_size, void* d_ws, size_t ws_size,
                              hipStream_t stream) {
  const int N = 8192, D = 768, DFF = 2048;
  const float* Q  = (const float*)d_in[0];
  const float* Km = (const float*)d_in[1];
  const float* V  = (const float*)d_in[2];
  const float* W1 = (const float*)d_in[3];
  const float* b1 = (const float*)d_in[4];
  const float* W2 = (const float*)d_in[5];
  const float* b2 = (const float*)d_in[6];

  char* w = (char*)d_ws;
  size_t off = 0;
  auto take = [&](size_t bytes) { void* p = w + off; off += bytes; return p; };
  unsigned short* qh   = (unsigned short*)take((size_t)N * D * 2);
  unsigned short* kh   = (unsigned short*)take((size_t)N * D * 2);
  unsigned short* vT   = (unsigned short*)take((size_t)N * D * 2);
  unsigned short* ctx16= (unsigned short*)take((size_t)N * D * 2);
  float*          ctx32= (float*)take((size_t)N * D * 4);
  unsigned short* hb   = (unsigned short*)take((size_t)N * DFF * 2);
  unsigned short* w1h  = (unsigned short*)take((size_t)DFF * D * 2);
  unsigned short* w2h  = (unsigned short*)take((size_t)D * DFF * 2);
  float*          stm  = (float*)take((size_t)64 * N * 4);
  float*          stl  = (float*)take((size_t)64 * N * 4);
  unsigned short* alp  = (unsigned short*)take((size_t)N * 64 * 2);
  unsigned short* Pp   = (unsigned short*)take((size_t)N * N * 2);  // P' fp16, 128 MB
  (void)ws_size;

  cvt_f16<<<(N * D) / 256, 256, 0, stream>>>(Q, qh, N * D);
  cvt_f16<<<(N * D) / 256, 256, 0, stream>>>(Km, kh, N * D);
  vt_kernel<<<dim3(D / 32, N / 32), dim3(32, 8), 0, stream>>>(V, vT);
  cvt_f16<<<(DFF * D) / 256, 256, 0, stream>>>(W1, w1h, DFF * D);
  cvt_f16<<<(D * DFF) / 256, 256, 0, stream>>>(W2, w2h, D * DFF);
  hipMemsetAsync(ctx32, 0, (size_t)N * D * 4, stream);
  bias_fill<<<(N * D) / 256, 256, 0, stream>>>((float*)d_out, b2, D);

  {  // QK^T with fused exp + stats: P' fp16 [8192x8192], m/l per (row,tile)
    const int nt = N / 128, mt = N / 128;
    gemm_nt<128, 128, 3, false, false, false, 0>
        <<<nt * mt, 256, 0, stream>>>(
            qh, kh, Pp, nullptr, nullptr, stm, stl, N,
            D, D, D, N, nt, mt, 1);
  }
  combine_alpha<<<N / 4, 256, 0, stream>>>(stm, stl, alp, 64, N);
  {  // ctx32 += (alpha .* P') . V  — split-K sl=2, fp32 atomics
    const int nt = D / 128, mt = N / 128, sl = 2;
    gemm_nt<128, 128, 2, false, false, true, 1>
        <<<nt * mt * sl, 256, 0, stream>>>(
            Pp, vT, ctx32, nullptr, alp, nullptr, nullptr, N,
            N / sl, N, N, D, nt, mt, sl);
  }
  cvt_f16<<<(N * D) / 256, 256, 0, stream>>>(ctx32, ctx16, N * D);

  {  // h = relu(ctx . W1^T + b1)  fp16
    const int nt = DFF / 128, mt = N / 128;
    gemm_nt<128, 128, 0, true, true, false, 1>
        <<<nt * mt, 256, 0, stream>>>(
            ctx16, w1h, hb, b1, nullptr, nullptr, nullptr, N,
            D, D, D, DFF, nt, mt, 1);
  }
  {  // out += h . W2^T  (bias pre-filled) — split-K sl=2, fp32 atomics
    const int nt = D / 128, mt = N / 128, sl = 2;
    gemm_nt<128, 128, 2, false, false, false, 1>
        <<<nt * mt * sl, 256, 0, stream>>>(
            hb, w2h, (float*)d_out, nullptr, nullptr, nullptr, nullptr, N,
            DFF / sl, DFF, DFF, D, nt, mt, sl);
  }
}

// Round 5
// 642.151 us; speedup vs baseline: 1.9771x; 1.0586x over previous
//
#include <hip/hip_runtime.h>
#include <cstdint>

#define DEV __device__ __forceinline__

typedef _Float16 f16;
typedef __attribute__((ext_vector_type(8))) _Float16 f16x8;
typedef __attribute__((ext_vector_type(4))) float f32x4;

DEV unsigned short f2h(float f) {
  f16 h = (f16)f;
  return __builtin_bit_cast(unsigned short, h);
}

DEV void async_ld16(const void* g, void* l) {
  __builtin_amdgcn_global_load_lds(
      (__attribute__((address_space(1))) unsigned int*)(uintptr_t)g,
      (__attribute__((address_space(3))) unsigned int*)(uint32_t)(uintptr_t)l,
      16, 0, 0);
}

// ---------------------------------------------------------------------------
// NT-GEMM: C[M x N] = A[M x K] * B[N x K]^T   (K-contiguous, f16-as-ushort)
// 128x128 tile, BK=32, 4 waves (2x2), 16x16x32 f16 MFMA, global_load_lds x16.
// EPI: 0 = fp16 store, 1 = fp32 store, 2 = fp32 atomicAdd, 3 = exp+stats
//      (writes P' = exp(S - m_tile) fp16 + per-(row,tile) m/l stats).
// ALPHA: scale A-fragments in-loop by alphaT[ktile][row] (fp16).
//   alp global layout is TRANSPOSED: alp[tile * Mtot + row]. The kernel stages
//   the slice-local (K/128) x BM block into LDS as Alds[tile*128 + row] so the
//   16 fragment lanes read 32 consecutive bytes -> conflict-free (R4 fix:
//   the row-major layout made all 16 lanes hit one bank, 6e7 conflict cycles).
// ORDER: within-XCD block order: 0 = mloc-inner, 1 = rest-inner.
// Grid is 1D = nt*mt*sl; sl = split-K slices (K param = per-slice depth).
// ---------------------------------------------------------------------------
template <int BM, int BN, int EPI, bool RELU, bool HASBIAS, bool ALPHA, int ORDER>
__global__ __launch_bounds__(256) void gemm_nt(
    const unsigned short* __restrict__ A, const unsigned short* __restrict__ B,
    void* __restrict__ Cp, const float* __restrict__ bias,
    const unsigned short* __restrict__ alp, float* __restrict__ stm,
    float* __restrict__ stl, int Mtot,
    int K, int lda, int ldb, int ldc, int nt, int mt, int sl) {
  constexpr int BK = 32;
  constexpr int WM = BM / 2, WN = BN / 2;
  constexpr int FM = WM / 16, FN = WN / 16;

  __shared__ __align__(16) unsigned short As[BM * BK];
  __shared__ __align__(16) unsigned short Bs[BN * BK];
  __shared__ __align__(16) unsigned short Alds[ALPHA ? BM * 32 : 8];  // 32 tiles x 128 rows

  // ---- XCD-aware swizzle (HW maps linear block id round-robin over 8 XCDs) -
  int mb, nb, zb;
  {
    const int b = blockIdx.x;
    if ((mt & 7) == 0) {
      const int xcd = b & 7;
      const int i = b >> 3;
      const int band_sz = 8 * nt * sl;
      const int band = i / band_sz;
      const int wq = i % band_sz;
      int mloc, rest;
      if (ORDER == 0) { mloc = wq & 7; rest = wq >> 3; }
      else           { rest = wq % (nt * sl); mloc = wq / (nt * sl); }
      mb = xcd + 8 * (band * 8 + mloc);
      nb = rest % nt;
      zb = rest / nt;
    } else {
      nb = b % nt;
      const int t = b / nt;
      mb = t % mt;
      zb = t / mt;
    }
  }

  const int tid = threadIdx.x;
  const int wave = tid >> 6, lane = tid & 63;
  const int wm = (wave >> 1) * WM, wn = (wave & 1) * WN;
  const int bm = mb * BM, bn = nb * BN;
  const size_t koff = (size_t)zb * K;

  const int r4 = tid >> 2;
  const int c4 = (tid & 3) * 8;

  if (ALPHA) {
    // stage alphaT slice: (K/128) tiles x BM rows fp16 (8 KB at K=4096,BM=128)
    const int ntile_l = K >> 7;                      // tiles in this slice
    const int nu4 = (ntile_l * BM) >> 3;             // uint4 units (BM==128 -> 16/tile)
    const unsigned short* g0 = alp + (size_t)(zb * ntile_l) * Mtot + bm;
    uint4* s = (uint4*)Alds;
    for (int idx = tid; idx < nu4; idx += 256) {
      const int t = idx >> 4;                        // tile (16 uint4 per 128 rows)
      const int ru = (idx & 15) << 3;                // row offset
      s[idx] = *(const uint4*)(g0 + (size_t)t * Mtot + ru);
    }
  }

  f32x4 acc[FM][FN] = {};

  const int kq = (lane >> 4) * 8;
  const int mr = lane & 15;
  const int quad = lane >> 4;

  for (int k0 = 0; k0 < K; k0 += BK) {
#pragma unroll
    for (int p = 0; p < BM / 64; ++p) {
      const unsigned short* g = A + (size_t)(bm + p * 64 + r4) * lda + koff + k0 + c4;
      async_ld16(g, &As[p * 2048 + wave * 512]);
    }
#pragma unroll
    for (int p = 0; p < BN / 64; ++p) {
      const unsigned short* g = B + (size_t)(bn + p * 64 + r4) * ldb + koff + k0 + c4;
      async_ld16(g, &Bs[p * 2048 + wave * 512]);
    }
    __syncthreads();

    f16x8 av[FM], bv[FN];
#pragma unroll
    for (int i = 0; i < FM; ++i)
      av[i] = *(const f16x8*)(const void*)&As[(wm + i * 16 + mr) * BK + kq];
#pragma unroll
    for (int j = 0; j < FN; ++j)
      bv[j] = *(const f16x8*)(const void*)&Bs[(wn + j * 16 + mr) * BK + kq];

    if (ALPHA) {
      const int tl = k0 >> 7;  // slice-local tile
#pragma unroll
      for (int i = 0; i < FM; ++i) {
        const f16 sc = ((const f16*)Alds)[tl * 128 + (wm + i * 16 + mr)];
        av[i] = av[i] * sc;
      }
    }

#pragma unroll
    for (int i = 0; i < FM; ++i)
#pragma unroll
      for (int j = 0; j < FN; ++j)
        acc[i][j] = __builtin_amdgcn_mfma_f32_16x16x32_f16(av[i], bv[j], acc[i][j], 0, 0, 0);

    __syncthreads();
  }

  if (EPI == 3) {
    // --- fused exp + per-(row, 128-tile) stats ---------------------------
    float* sred = (float*)As;   // [128][2]
    float* ssum = (float*)Bs;   // [128][2]
    const int wc = wave & 1;
    float mt_[FM][4];
#pragma unroll
    for (int i = 0; i < FM; ++i)
#pragma unroll
      for (int r = 0; r < 4; ++r) {
        float m = acc[i][0][r];
#pragma unroll
        for (int j = 1; j < FN; ++j) m = fmaxf(m, acc[i][j][r]);
        m = fmaxf(m, __shfl_xor(m, 1));
        m = fmaxf(m, __shfl_xor(m, 2));
        m = fmaxf(m, __shfl_xor(m, 4));
        m = fmaxf(m, __shfl_xor(m, 8));
        if (mr == 0) sred[(wm + i * 16 + quad * 4 + r) * 2 + wc] = m;
      }
    __syncthreads();
#pragma unroll
    for (int i = 0; i < FM; ++i)
#pragma unroll
      for (int r = 0; r < 4; ++r) {
        const int row_l = wm + i * 16 + quad * 4 + r;
        mt_[i][r] = fmaxf(sred[row_l * 2], sred[row_l * 2 + 1]);
        float l = 0.f;
#pragma unroll
        for (int j = 0; j < FN; ++j) {
          float e = __expf(acc[i][j][r] - mt_[i][r]);
          ((unsigned short*)Cp)[(size_t)(bm + row_l) * ldc + (bn + wn + j * 16 + mr)] = f2h(e);
          l += e;
        }
        l += __shfl_xor(l, 1);
        l += __shfl_xor(l, 2);
        l += __shfl_xor(l, 4);
        l += __shfl_xor(l, 8);
        if (mr == 0) ssum[row_l * 2 + wc] = l;
      }
    __syncthreads();
    if (wc == 0 && mr == 0) {
#pragma unroll
      for (int i = 0; i < FM; ++i)
#pragma unroll
        for (int r = 0; r < 4; ++r) {
          const int row_l = wm + i * 16 + quad * 4 + r;
          stm[(size_t)nb * Mtot + bm + row_l] = mt_[i][r];
          stl[(size_t)nb * Mtot + bm + row_l] = ssum[row_l * 2] + ssum[row_l * 2 + 1];
        }
    }
    return;
  }

  // --- standard epilogue ---------------------------------------------------
#pragma unroll
  for (int i = 0; i < FM; ++i) {
#pragma unroll
    for (int j = 0; j < FN; ++j) {
      const int col = bn + wn + j * 16 + mr;
      float bv_ = 0.f;
      if (HASBIAS) bv_ = bias[col];
#pragma unroll
      for (int r = 0; r < 4; ++r) {
        const int row = bm + wm + i * 16 + quad * 4 + r;
        float v = acc[i][j][r];
        if (HASBIAS) v += bv_;
        if (RELU) v = fmaxf(v, 0.f);
        if (EPI == 2)
          atomicAdd(&((float*)Cp)[(size_t)row * ldc + col], v);
        else if (EPI == 1)
          ((float*)Cp)[(size_t)row * ldc + col] = v;
        else
          ((unsigned short*)Cp)[(size_t)row * ldc + col] = f2h(v);
      }
    }
  }
}

// per-row combine: M = max_t m_t, L = sum_t l_t*exp(m_t-M)
// writes alpha TRANSPOSED: alp[tile * Mtot + row] = exp(m_t - M) / L
__global__ __launch_bounds__(256) void combine_alpha(
    const float* __restrict__ stm, const float* __restrict__ stl,
    unsigned short* __restrict__ alp, int ntile, int Mtot) {
  const int row = blockIdx.x * 4 + (threadIdx.x >> 6);
  const int t = threadIdx.x & 63;
  float m = (t < ntile) ? stm[(size_t)t * Mtot + row] : -1e30f;
  float M = m;
#pragma unroll
  for (int o = 1; o < 64; o <<= 1) M = fmaxf(M, __shfl_xor(M, o));
  float l = (t < ntile) ? stl[(size_t)t * Mtot + row] : 0.f;
  float c = l * __expf(m - M);
#pragma unroll
  for (int o = 1; o < 64; o <<= 1) c += __shfl_xor(c, o);
  if (t < ntile) alp[(size_t)t * Mtot + row] = f2h(__expf(m - M) / c);
}

__global__ __launch_bounds__(256) void cvt_f16(const float* __restrict__ in,
                                               unsigned short* __restrict__ out, int n) {
  int i = blockIdx.x * 256 + threadIdx.x;
  if (i < n) out[i] = f2h(in[i]);
}

__global__ __launch_bounds__(256) void bias_fill(float* __restrict__ out,
                                                 const float* __restrict__ b, int d) {
  int i = blockIdx.x * 256 + threadIdx.x;
  out[i] = b[i % d];
}

// V [8192 x 768] fp32 -> vT [768 x 8192] fp16
__global__ __launch_bounds__(256) void vt_kernel(const float* __restrict__ V,
                                                 unsigned short* __restrict__ vT) {
  __shared__ float t[32][33];
  const int bx = blockIdx.x, by = blockIdx.y;
  const int x = threadIdx.x, y = threadIdx.y;  // (32, 8)
#pragma unroll
  for (int r = 0; r < 4; ++r)
    t[y + r * 8][x] = V[(size_t)(by * 32 + y + r * 8) * 768 + bx * 32 + x];
  __syncthreads();
#pragma unroll
  for (int r = 0; r < 4; ++r)
    vT[(size_t)(bx * 32 + y + r * 8) * 8192 + by * 32 + x] = f2h(t[x][y + r * 8]);
}

// ---------------------------------------------------------------------------
extern "C" void kernel_launch(void* const* d_in, const int* in_sizes, int n_in,
                              void* d_out, int out_size, void* d_ws, size_t ws_size,
                              hipStream_t stream) {
  const int N = 8192, D = 768, DFF = 2048;
  const float* Q  = (const float*)d_in[0];
  const float* Km = (const float*)d_in[1];
  const float* V  = (const float*)d_in[2];
  const float* W1 = (const float*)d_in[3];
  const float* b1 = (const float*)d_in[4];
  const float* W2 = (const float*)d_in[5];
  const float* b2 = (const float*)d_in[6];

  char* w = (char*)d_ws;
  size_t off = 0;
  auto take = [&](size_t bytes) { void* p = w + off; off += bytes; return p; };
  unsigned short* qh   = (unsigned short*)take((size_t)N * D * 2);
  unsigned short* kh   = (unsigned short*)take((size_t)N * D * 2);
  unsigned short* vT   = (unsigned short*)take((size_t)N * D * 2);
  unsigned short* ctx16= (unsigned short*)take((size_t)N * D * 2);
  float*          ctx32= (float*)take((size_t)N * D * 4);
  unsigned short* hb   = (unsigned short*)take((size_t)N * DFF * 2);
  unsigned short* w1h  = (unsigned short*)take((size_t)DFF * D * 2);
  unsigned short* w2h  = (unsigned short*)take((size_t)D * DFF * 2);
  float*          stm  = (float*)take((size_t)64 * N * 4);
  float*          stl  = (float*)take((size_t)64 * N * 4);
  unsigned short* alp  = (unsigned short*)take((size_t)64 * N * 2);  // [tile][row]
  unsigned short* Pp   = (unsigned short*)take((size_t)N * N * 2);   // P' fp16, 128 MB
  (void)ws_size;

  cvt_f16<<<(N * D) / 256, 256, 0, stream>>>(Q, qh, N * D);
  cvt_f16<<<(N * D) / 256, 256, 0, stream>>>(Km, kh, N * D);
  vt_kernel<<<dim3(D / 32, N / 32), dim3(32, 8), 0, stream>>>(V, vT);
  cvt_f16<<<(DFF * D) / 256, 256, 0, stream>>>(W1, w1h, DFF * D);
  cvt_f16<<<(D * DFF) / 256, 256, 0, stream>>>(W2, w2h, D * DFF);
  hipMemsetAsync(ctx32, 0, (size_t)N * D * 4, stream);
  bias_fill<<<(N * D) / 256, 256, 0, stream>>>((float*)d_out, b2, D);

  {  // QK^T with fused exp + stats: P' fp16 [8192x8192], m/l per (row,tile)
    const int nt = N / 128, mt = N / 128;
    gemm_nt<128, 128, 3, false, false, false, 0>
        <<<nt * mt, 256, 0, stream>>>(
            qh, kh, Pp, nullptr, nullptr, stm, stl, N,
            D, D, D, N, nt, mt, 1);
  }
  combine_alpha<<<N / 4, 256, 0, stream>>>(stm, stl, alp, 64, N);
  {  // ctx32 += (alphaT .* P') . V  — split-K sl=2, fp32 atomics
    const int nt = D / 128, mt = N / 128, sl = 2;
    gemm_nt<128, 128, 2, false, false, true, 1>
        <<<nt * mt * sl, 256, 0, stream>>>(
            Pp, vT, ctx32, nullptr, alp, nullptr, nullptr, N,
            N / sl, N, N, D, nt, mt, sl);
  }
  cvt_f16<<<(N * D) / 256, 256, 0, stream>>>(ctx32, ctx16, N * D);

  {  // h = relu(ctx . W1^T + b1)  fp16
    const int nt = DFF / 128, mt = N / 128;
    gemm_nt<128, 128, 0, true, true, false, 1>
        <<<nt * mt, 256, 0, stream>>>(
            ctx16, w1h, hb, b1, nullptr, nullptr, nullptr, N,
            D, D, D, DFF, nt, mt, 1);
  }
  {  // out += h . W2^T  (bias pre-filled) — split-K sl=2, fp32 atomics
    const int nt = D / 128, mt = N / 128, sl = 2;
    gemm_nt<128, 128, 2, false, false, false, 1>
        <<<nt * mt * sl, 256, 0, stream>>>(
            hb, w2h, (float*)d_out, nullptr, nullptr, nullptr, nullptr, N,
            DFF / sl, DFF, DFF, D, nt, mt, sl);
  }
}